// Round 7
// baseline (386.454 us; speedup 1.0000x reference)
//
#include <hip/hip_runtime.h>
#include <hip/hip_bf16.h>

typedef unsigned char uchar_t;
typedef __attribute__((ext_vector_type(4))) float f32x4;

#define B_SZ 8192
#define D_FT 784
#define K_PAD 832   // 13 * 64 fp8 bytes per row
#define N_KT 13
#define THRESH 0.9f

#define GLOBAL_AS(p) ((const __attribute__((address_space(1))) void*)(p))
#define LDS_AS(p)    ((__attribute__((address_space(3))) void*)(p))

// Wave-per-row preproc: 2048 blocks x 4 waves; wave w handles row blockIdx*4+w.
// conv 2x2/s2 + bias -> 4x4 unitary -> qf (LDS, fp32), row norm -> qn fp8 e4m3
// (packed via v_cvt_pk_fp8_f32, padded to 832), logits + log_softmax (fp32).
__global__ __launch_bounds__(256) void preproc_kernel(
    const float* __restrict__ x, const float* __restrict__ conv_w,
    const float* __restrict__ conv_b, const float* __restrict__ unitary,
    const float* __restrict__ lin_w, const float* __restrict__ lin_b,
    float* __restrict__ log_probs, uchar_t* __restrict__ qn)
{
    __shared__ float xr[4][784];
    __shared__ float qf[4][784];

    const int t = threadIdx.x, lane = t & 63, wave = t >> 6;
    const int b = blockIdx.x * 4 + wave;
    float* xw = xr[wave];
    float* qw = qf[wave];

    const float4* xsrc = (const float4*)(x + (size_t)b * 784);
    #pragma unroll
    for (int i = lane; i < 196; i += 64) ((float4*)xw)[i] = xsrc[i];
    __syncthreads();

    float sumsq = 0.f;
    for (int g = lane; g < 196; g += 64) {
        const int c = g / 49, p = g % 49;
        const float w00 = conv_w[c*4+0], w01 = conv_w[c*4+1];
        const float w10 = conv_w[c*4+2], w11 = conv_w[c*4+3];
        const float bcv = conv_b[c];
        float feat[4];
        #pragma unroll
        for (int j = 0; j < 4; ++j) {
            const int s = 4*p + j;
            const int h = s / 14, wq = s % 14;
            const float* px = &xw[(2*h)*28 + 2*wq];
            feat[j] = bcv + w00*px[0] + w01*px[1] + w10*px[28] + w11*px[29];
        }
        #pragma unroll
        for (int w = 0; w < 4; ++w) {
            float v = unitary[w*4+0]*feat[0] + unitary[w*4+1]*feat[1]
                    + unitary[w*4+2]*feat[2] + unitary[w*4+3]*feat[3];
            qw[4*g + w] = v;
            sumsq += v * v;
        }
    }
    __syncthreads();

    #pragma unroll
    for (int off = 1; off < 64; off <<= 1) sumsq += __shfl_xor(sumsq, off, 64);
    const float inv = 1.0f / (sqrtf(sumsq) + 1e-12f);

    // qn write: 208 uints (4 fp8 each) = 832 B, zero-padded past 784
    unsigned int* qrow = (unsigned int*)(qn + (size_t)b * K_PAD);
    for (int i = lane; i < 208; i += 64) {
        unsigned int o = 0u;
        if (i < 196) {
            const float v0 = qw[4*i+0] * inv, v1 = qw[4*i+1] * inv;
            const float v2 = qw[4*i+2] * inv, v3 = qw[4*i+3] * inv;
            int lo = __builtin_amdgcn_cvt_pk_fp8_f32(v0, v1, 0, 0);
            o = (unsigned int)__builtin_amdgcn_cvt_pk_fp8_f32(v2, v3, lo, 1);
        }
        qrow[i] = o;
    }

    float acc[10];
    #pragma unroll
    for (int cl = 0; cl < 10; ++cl) acc[cl] = 0.f;
    for (int k = lane; k < 784; k += 64) {
        const float v = qw[k];
        #pragma unroll
        for (int cl = 0; cl < 10; ++cl) acc[cl] += v * lin_w[cl*784 + k];
    }
    #pragma unroll
    for (int cl = 0; cl < 10; ++cl) {
        #pragma unroll
        for (int off = 1; off < 64; off <<= 1)
            acc[cl] += __shfl_xor(acc[cl], off, 64);
        acc[cl] += lin_b[cl];
    }
    if (lane == 0) {
        float mx = -1e30f;
        #pragma unroll
        for (int cl = 0; cl < 10; ++cl) mx = fmaxf(mx, acc[cl]);
        float se = 0.f;
        #pragma unroll
        for (int cl = 0; cl < 10; ++cl) se += expf(acc[cl] - mx);
        const float lse = mx + logf(se);
        #pragma unroll
        for (int cl = 0; cl < 10; ++cl)
            log_probs[(size_t)b*10 + cl] = acc[cl] - lse;
    }
}

// Symmetric 128x128-tile fp8 Gram GEMM, BK=64 (13 kt), 4 waves (64x64 tiles),
// LDS double-buffer with a SINGLE s_barrier per kt:
//   wait own vmcnt(0) [4 glds of buf p, issued one kt ago]
//   s_barrier          [=> all waves' buf-p chunks landed; all waves done
//                       reading buf p^1 during kt-1]
//   STAGE(p^1, kt+1)   [safe overwrite; full kt of MFMA to cover latency]
//   compute(p)
// LDS layout per 16-row block rb (1024 B): [kchunk 0..3][row 0..15][16 B];
// glds lane map row=lane&15, kchunk=lane>>4 matches exactly -> 0 conflicts.
__global__ __launch_bounds__(256, 4) void gram_kernel(
    const uchar_t* __restrict__ qn, float* __restrict__ adj)
{
    const int br = blockIdx.y, bc = blockIdx.x;
    if (br > bc) return;   // symmetry: upper-triangular block pairs only

    __shared__ uchar_t ldsA[2][8192] __attribute__((aligned(16)));  // 2x8KB
    __shared__ uchar_t ldsB[2][8192] __attribute__((aligned(16)));  // 2x8KB

    const int t = threadIdx.x;
    const int lane = t & 63, wave = t >> 6;
    const int wr = wave >> 1, wc = wave & 1;
    const int quad = lane >> 4, l16 = lane & 15;

    // staging: wave w stages row-blocks {w, w+4} of A and B (4 glds/kt)
    const int srow = lane & 15, sck = (lane >> 4) * 16;  // byte offset in row
    const uchar_t* gA0 = qn + (size_t)(br*128 + wave*16     + srow) * K_PAD + sck;
    const uchar_t* gA1 = qn + (size_t)(br*128 + (wave+4)*16 + srow) * K_PAD + sck;
    const uchar_t* gB0 = qn + (size_t)(bc*128 + wave*16     + srow) * K_PAD + sck;
    const uchar_t* gB1 = qn + (size_t)(bc*128 + (wave+4)*16 + srow) * K_PAD + sck;
    const int ld0 = wave * 1024, ld1 = (wave + 4) * 1024;

    #define STAGE(p, koff) do {                                                            \
        __builtin_amdgcn_global_load_lds(GLOBAL_AS(gA0 + (koff)), LDS_AS(&ldsA[p][ld0]), 16, 0, 0); \
        __builtin_amdgcn_global_load_lds(GLOBAL_AS(gA1 + (koff)), LDS_AS(&ldsA[p][ld1]), 16, 0, 0); \
        __builtin_amdgcn_global_load_lds(GLOBAL_AS(gB0 + (koff)), LDS_AS(&ldsB[p][ld0]), 16, 0, 0); \
        __builtin_amdgcn_global_load_lds(GLOBAL_AS(gB1 + (koff)), LDS_AS(&ldsB[p][ld1]), 16, 0, 0); \
    } while (0)

    f32x4 acc[4][4] = {};
    STAGE(0, 0);

    for (int kt = 0; kt < N_KT; ++kt) {
        const int p = kt & 1;
        asm volatile("" ::: "memory");
        __builtin_amdgcn_s_waitcnt(0xF70);   // vmcnt(0): own buf-p glds done
        __builtin_amdgcn_s_barrier();        // single barrier per kt
        asm volatile("" ::: "memory");
        if (kt + 1 < N_KT)
            STAGE(p ^ 1, (kt + 1) * 64);     // prefetch next tile (other buf)
        asm volatile("" ::: "memory");

        #pragma unroll
        for (int s = 0; s < 2; ++s) {
            const int fo = (2*s + (quad >> 1))*256 + l16*16 + (quad & 1)*8;
            long bfr[4];
            #pragma unroll
            for (int ni = 0; ni < 4; ++ni)
                bfr[ni] = *(const long*)&ldsB[p][(wc*4 + ni)*1024 + fo];
            #pragma unroll
            for (int mi = 0; mi < 4; ++mi) {
                const long af = *(const long*)&ldsA[p][(wr*4 + mi)*1024 + fo];
                #pragma unroll
                for (int ni = 0; ni < 4; ++ni)
                    acc[mi][ni] = __builtin_amdgcn_mfma_f32_16x16x32_fp8_fp8(
                        af, bfr[ni], acc[mi][ni], 0, 0, 0);
            }
        }
    }
    #undef STAGE

    // epilogue: fid = c^2, threshold, zero diagonal; off-diag tiles also
    // store the transpose (float4 over 4 consecutive acc rows).
    const bool offdiag = (br != bc);
    #pragma unroll
    for (int mi = 0; mi < 4; ++mi) {
        const int gr0 = br*128 + wr*64 + mi*16 + quad*4;
        #pragma unroll
        for (int ni = 0; ni < 4; ++ni) {
            const int gc = bc*128 + wc*64 + ni*16 + l16;
            const f32x4 v = acc[mi][ni];
            float o[4];
            #pragma unroll
            for (int r = 0; r < 4; ++r)
                o[r] = (v[r]*v[r] >= THRESH && (gr0 + r) != gc) ? 1.0f : 0.0f;
            #pragma unroll
            for (int r = 0; r < 4; ++r)
                adj[(size_t)(gr0 + r) * B_SZ + gc] = o[r];
            if (offdiag)
                *(float4*)&adj[(size_t)gc * B_SZ + gr0] =
                    make_float4(o[0], o[1], o[2], o[3]);
        }
    }
}

extern "C" void kernel_launch(void* const* d_in, const int* in_sizes, int n_in,
                              void* d_out, int out_size, void* d_ws, size_t ws_size,
                              hipStream_t stream) {
    const float* x       = (const float*)d_in[0];
    const float* conv_w  = (const float*)d_in[1];
    const float* conv_b  = (const float*)d_in[2];
    const float* unitary = (const float*)d_in[3];
    const float* lin_w   = (const float*)d_in[4];
    const float* lin_b   = (const float*)d_in[5];

    float* log_probs = (float*)d_out;
    float* adj       = (float*)d_out + (size_t)B_SZ * 10;
    uchar_t* qn      = (uchar_t*)d_ws;   // [8192, 832] fp8 e4m3

    preproc_kernel<<<B_SZ / 4, 256, 0, stream>>>(x, conv_w, conv_b, unitary,
                                                 lin_w, lin_b, log_probs, qn);
    gram_kernel<<<dim3(64, 64), 256, 0, stream>>>(qn, adj);
}